// Round 3
// baseline (126.608 us; speedup 1.0000x reference)
//
#include <hip/hip_runtime.h>

// Fused: y1 = valid cross-corr(X, W) [4095x4095]; y2 = transposed-conv(y1, W) [4096x4096]
//   y2[i,j] = sum_{a,b in {0,1}} W[a,b] * y1(i-a, j-b),  y1 masked to 0 outside [0,4095)^2
//   y1(p,q) = W00*X[p][q] + W01*X[p][q+1] + W10*X[p+1][q] + W11*X[p+1][q+1]
// Each thread: 4 consecutive outputs (float4), 3x6 X footprint, 10 masked y1 values.

#define HD 4096
#define QPR (HD / 4)  // quads per row = 1024

__global__ __launch_bounds__(256) void fused_conv_kernel(
    const float* __restrict__ X, const float* __restrict__ Wk,
    float* __restrict__ Y)
{
    const int idx = blockIdx.x * blockDim.x + threadIdx.x;
    const int i  = idx >> 10;          // output row (QPR == 1024)
    const int j0 = (idx & (QPR - 1)) << 2;  // first output col of this quad
    if (i >= HD) return;

    // W is uniform across all threads -> scalar loads
    const float w00 = Wk[0], w01 = Wk[1], w10 = Wk[2], w11 = Wk[3];

    // Load X rows i-1..i+1, cols j0-1..j0+4 (zero-fill OOB; OOB values only
    // ever feed y1 terms that are masked to zero anyway, except edge cols,
    // which is why y1 masking below is explicit).
    float x[3][6];
    #pragma unroll
    for (int r = 0; r < 3; ++r) {
        const int row = i - 1 + r;
        if (row >= 0 && row < HD) {
            const float* rp = X + (size_t)row * HD;
            const float4 v = *reinterpret_cast<const float4*>(rp + j0);
            x[r][1] = v.x; x[r][2] = v.y; x[r][3] = v.z; x[r][4] = v.w;
            x[r][0] = (j0 > 0)      ? rp[j0 - 1] : 0.f;
            x[r][5] = (j0 + 4 < HD) ? rp[j0 + 4] : 0.f;
        } else {
            #pragma unroll
            for (int c = 0; c < 6; ++c) x[r][c] = 0.f;
        }
    }

    // y1 values needed: rows {i-1, i} x cols {j0-1 .. j0+3}
    // y1(prow,qcol) valid iff 0 <= prow <= HD-2 and 0 <= qcol <= HD-2
    float y1v[2][5];
    #pragma unroll
    for (int p = 0; p < 2; ++p) {
        const int prow = i - 1 + p;
        const bool pv = (prow >= 0) && (prow < HD - 1);
        #pragma unroll
        for (int q = 0; q < 5; ++q) {
            const int qcol = j0 - 1 + q;
            const bool qv = (qcol >= 0) && (qcol < HD - 1);
            const float v = w00 * x[p][q]     + w01 * x[p][q + 1]
                          + w10 * x[p + 1][q] + w11 * x[p + 1][q + 1];
            y1v[p][q] = (pv && qv) ? v : 0.f;
        }
    }

    // y2[i, j0+t] = W00*y1(i, j) + W01*y1(i, j-1) + W10*y1(i-1, j) + W11*y1(i-1, j-1)
    float4 out;
    out.x = w00 * y1v[1][1] + w01 * y1v[1][0] + w10 * y1v[0][1] + w11 * y1v[0][0];
    out.y = w00 * y1v[1][2] + w01 * y1v[1][1] + w10 * y1v[0][2] + w11 * y1v[0][1];
    out.z = w00 * y1v[1][3] + w01 * y1v[1][2] + w10 * y1v[0][3] + w11 * y1v[0][2];
    out.w = w00 * y1v[1][4] + w01 * y1v[1][3] + w10 * y1v[0][4] + w11 * y1v[0][3];
    *reinterpret_cast<float4*>(Y + (size_t)i * HD + j0) = out;
}

extern "C" void kernel_launch(void* const* d_in, const int* in_sizes, int n_in,
                              void* d_out, int out_size, void* d_ws, size_t ws_size,
                              hipStream_t stream) {
    const float* X  = (const float*)d_in[0];
    const float* Wk = (const float*)d_in[1];
    float* Y        = (float*)d_out;

    const int total_threads = HD * QPR;           // 4096 * 1024 = 4,194,304
    const int block = 256;
    const int grid  = total_threads / block;      // 16384 blocks
    fused_conv_kernel<<<grid, block, 0, stream>>>(X, Wk, Y);
}

// Round 4
// 120.146 us; speedup vs baseline: 1.0538x; 1.0538x over previous
//
#include <hip/hip_runtime.h>

// Fused: y1 = valid cross-corr(X, W) [4095x4095]; y2 = transposed-conv(y1, W) [4096x4096]
//   y2[i,j] = sum_{a,b in {0,1}} W[a,b] * y1(i-a, j-b),  y1 masked to 0 outside [0,4095)^2
//   y1(p,q) = W00*X[p][q] + W01*X[p][q+1] + W10*X[p+1][q] + W11*X[p+1][q+1]
//
// R3 counters: FETCH 68.6MB (ideal), WRITE 65.5MB (ideal), but only 39% HBM peak,
// VALUBusy 27% -> issue/latency-bound, not traffic-bound. Fix: 8-row register
// blocking. Each thread: 8x4 output tile, streaming 2-row X window.
// VMEM per quad: 10 -> 4.75. Grid 2048 blocks = 8 blocks/CU (one machine fill).

#define HD 4096
#define QPR 1024   // float4 quads per row
#define RB 8       // output rows per thread

__device__ __forceinline__ void load_row(const float* __restrict__ X, int row,
                                         int j0, float x[6]) {
    if (row >= 0 && row < HD) {
        const float* rp = X + (size_t)row * HD;
        const float4 v = *reinterpret_cast<const float4*>(rp + j0);
        x[1] = v.x; x[2] = v.y; x[3] = v.z; x[4] = v.w;
        x[0] = (j0 > 0)      ? rp[j0 - 1] : 0.f;
        x[5] = (j0 + 4 < HD) ? rp[j0 + 4] : 0.f;
    } else {
        #pragma unroll
        for (int c = 0; c < 6; ++c) x[c] = 0.f;
    }
}

__global__ __launch_bounds__(256) void fused_conv_kernel(
    const float* __restrict__ X, const float* __restrict__ Wk,
    float* __restrict__ Y)
{
    const int idx  = blockIdx.x * blockDim.x + threadIdx.x;
    const int i0   = (idx >> 10) * RB;          // first output row of tile
    const int j0   = (idx & (QPR - 1)) << 2;    // first output col of quad

    const float w00 = Wk[0], w01 = Wk[1], w10 = Wk[2], w11 = Wk[3];

    // Column validity of y1 col (j0-1+q): 0 <= qcol <= HD-2
    bool qv[5];
    #pragma unroll
    for (int q = 0; q < 5; ++q) {
        const int qc = j0 - 1 + q;
        qv[q] = (qc >= 0) && (qc < HD - 1);
    }

    // Streaming 2-row window: xb = X row i, xa = X row i+1 (rotating)
    float xa[6], xb[6];
    load_row(X, i0 - 1, j0, xa);
    load_row(X, i0,     j0, xb);

    // y1 row (i0-1): uses X rows i0-1, i0. Valid iff i0-1 >= 0 (upper bound
    // i0-1 <= HD-2 always holds since i0 <= HD-RB).
    float y1p[5];
    {
        const bool pv = (i0 - 1 >= 0);
        #pragma unroll
        for (int q = 0; q < 5; ++q) {
            const float v = w00 * xa[q] + w01 * xa[q + 1]
                          + w10 * xb[q] + w11 * xb[q + 1];
            y1p[q] = (pv && qv[q]) ? v : 0.f;
        }
    }

    #pragma unroll
    for (int r = 0; r < RB; ++r) {
        const int i = i0 + r;
        // xa <- X row i+1 (old xa dead); xb holds X row i
        load_row(X, i + 1, j0, xa);

        // y1 row i: valid iff i <= HD-2 (i >= 0 always)
        float y1c[5];
        const bool pv = (i < HD - 1);
        #pragma unroll
        for (int q = 0; q < 5; ++q) {
            const float v = w00 * xb[q] + w01 * xb[q + 1]
                          + w10 * xa[q] + w11 * xa[q + 1];
            y1c[q] = (pv && qv[q]) ? v : 0.f;
        }

        // y2[i, j0+t] = W00*y1(i,j) + W01*y1(i,j-1) + W10*y1(i-1,j) + W11*y1(i-1,j-1)
        float4 out;
        out.x = w00 * y1c[1] + w01 * y1c[0] + w10 * y1p[1] + w11 * y1p[0];
        out.y = w00 * y1c[2] + w01 * y1c[1] + w10 * y1p[2] + w11 * y1p[1];
        out.z = w00 * y1c[3] + w01 * y1c[2] + w10 * y1p[3] + w11 * y1p[2];
        out.w = w00 * y1c[4] + w01 * y1c[3] + w10 * y1p[4] + w11 * y1p[3];
        *reinterpret_cast<float4*>(Y + (size_t)i * HD + j0) = out;

        // rotate window (full unroll -> register renaming, copies are free)
        #pragma unroll
        for (int q = 0; q < 5; ++q) y1p[q] = y1c[q];
        #pragma unroll
        for (int c = 0; c < 6; ++c) xb[c] = xa[c];
    }
}

extern "C" void kernel_launch(void* const* d_in, const int* in_sizes, int n_in,
                              void* d_out, int out_size, void* d_ws, size_t ws_size,
                              hipStream_t stream) {
    const float* X  = (const float*)d_in[0];
    const float* Wk = (const float*)d_in[1];
    float* Y        = (float*)d_out;

    const int total_threads = (HD / RB) * QPR;    // 512 * 1024 = 524,288
    const int block = 256;
    const int grid  = total_threads / block;      // 2048 blocks = 8/CU
    fused_conv_kernel<<<grid, block, 0, stream>>>(X, Wk, Y);
}

// Round 5
// 116.090 us; speedup vs baseline: 1.0906x; 1.0349x over previous
//
#include <hip/hip_runtime.h>

// Fused: y1 = valid cross-corr(X,W) [4095x4095]; y2 = transposed-conv(y1,W) [4096x4096]
//   y2[i,j] = sum_{a,b} W[a,b]*y1(i-a,j-b), y1 masked to [0,4095)^2
//   y1(p,q) = W00*X[p][q] + W01*X[p][q+1] + W10*X[p+1][q] + W11*X[p+1][q+1]
//
// R3/R4 evidence: traffic ideal (FETCH 68.6MB/WRITE 65.5MB) but only ~40-55% of
// the 6.5 TB/s the harness's fill kernels prove achievable. Strided scalar edge
// loads did ~2x the needed cache-line work. This version: halos via wave
// shuffle (__shfl_up/__shfl_down), ONE 2-lane predicated edge load per row,
// all 10 row loads issued upfront (MLP=10), nontemporal Y stores (Y never
// re-read; don't evict X from L2).

#define HD 4096
#define QPR 1024   // float4 quads per row
#define RB 8       // output rows per thread

typedef float f32x4 __attribute__((ext_vector_type(4)));

__global__ __launch_bounds__(256) void fused_conv_kernel(
    const float* __restrict__ X, const float* __restrict__ Wk,
    float* __restrict__ Y)
{
    const int idx  = blockIdx.x * blockDim.x + threadIdx.x;
    const int i0   = (idx >> 10) * RB;          // first output row of tile
    const int j0   = (idx & (QPR - 1)) << 2;    // first output col of quad
    const int lane = threadIdx.x & 63;

    const float w00 = Wk[0], w01 = Wk[1], w10 = Wk[2], w11 = Wk[3];

    // X rows i0-1 .. i0+8, cols j0-1 .. j0+4. Row index is wave-uniform.
    // Lane l's left halo (col j0-1) == lane l-1's v.w; right halo == lane
    // l+1's v.x. Wave-edge lanes (0 and 63) fetch theirs with one shared
    // 2-lane predicated scalar load (returns 0 at the image border).
    float x[RB + 2][6];
    #pragma unroll
    for (int r = 0; r < RB + 2; ++r) {
        const int row = i0 - 1 + r;
        if (row >= 0 && row < HD) {
            const float* rp = X + (size_t)row * HD;
            const f32x4 v = *reinterpret_cast<const f32x4*>(rp + j0);
            float lft = __shfl_up(v[3], 1);      // lanes 1..63 valid
            float rgt = __shfl_down(v[0], 1);    // lanes 0..62 valid
            const int  eoff = (lane == 0) ? (j0 - 1) : (j0 + 4);
            const bool need = ((lane == 0) || (lane == 63)) &&
                              (eoff >= 0) && (eoff < HD);
            const float ev  = need ? rp[eoff] : 0.f;  // single 2-lane load
            if (lane == 0)  lft = ev;   // ev==0 at j0==0  (image left edge)
            if (lane == 63) rgt = ev;   // ev==0 at j0+4==HD (image right edge)
            x[r][0] = lft;  x[r][1] = v[0]; x[r][2] = v[1];
            x[r][3] = v[2]; x[r][4] = v[3]; x[r][5] = rgt;
        } else {
            #pragma unroll
            for (int c = 0; c < 6; ++c) x[r][c] = 0.f;
        }
    }

    // y1 col validity: qcol = j0-1+q in [0, HD-2].
    // q=0 needs j0>0; q=1..3 always valid; q=4 needs j0+4<HD.
    const bool lv = (j0 > 0);
    const bool rv = (j0 + 4 < HD);

    // y1 row p = i0-1+rr from x[rr], x[rr+1]; valid iff 0 <= p <= HD-2.
    float y1p[5], y1c[5];
    {
        const bool pv = (i0 > 0);   // p = i0-1; upper bound always holds
        #pragma unroll
        for (int q = 0; q < 5; ++q) {
            const float v = w00 * x[0][q] + w01 * x[0][q + 1]
                          + w10 * x[1][q] + w11 * x[1][q + 1];
            const bool ok = pv && (q != 0 || lv) && (q != 4 || rv);
            y1p[q] = ok ? v : 0.f;
        }
    }

    #pragma unroll
    for (int r = 0; r < RB; ++r) {
        const int i = i0 + r;                 // output row; y1 row p = i
        const bool pv = (i < HD - 1);         // p >= 0 always here
        #pragma unroll
        for (int q = 0; q < 5; ++q) {
            const float v = w00 * x[r + 1][q] + w01 * x[r + 1][q + 1]
                          + w10 * x[r + 2][q] + w11 * x[r + 2][q + 1];
            const bool ok = pv && (q != 0 || lv) && (q != 4 || rv);
            y1c[q] = ok ? v : 0.f;
        }

        // y2[i, j0+t] = W00*y1(i,j) + W01*y1(i,j-1) + W10*y1(i-1,j) + W11*y1(i-1,j-1)
        f32x4 o;
        o[0] = w00 * y1c[1] + w01 * y1c[0] + w10 * y1p[1] + w11 * y1p[0];
        o[1] = w00 * y1c[2] + w01 * y1c[1] + w10 * y1p[2] + w11 * y1p[1];
        o[2] = w00 * y1c[3] + w01 * y1c[2] + w10 * y1p[3] + w11 * y1p[2];
        o[3] = w00 * y1c[4] + w01 * y1c[3] + w10 * y1p[4] + w11 * y1p[3];
        __builtin_nontemporal_store(o, reinterpret_cast<f32x4*>(Y + (size_t)i * HD + j0));

        #pragma unroll
        for (int q = 0; q < 5; ++q) y1p[q] = y1c[q];  // rename, not copy
    }
}

extern "C" void kernel_launch(void* const* d_in, const int* in_sizes, int n_in,
                              void* d_out, int out_size, void* d_ws, size_t ws_size,
                              hipStream_t stream) {
    const float* X  = (const float*)d_in[0];
    const float* Wk = (const float*)d_in[1];
    float* Y        = (float*)d_out;

    const int total_threads = (HD / RB) * QPR;    // 512 * 1024 = 524,288
    const int block = 256;
    const int grid  = total_threads / block;      // 2048 blocks
    fused_conv_kernel<<<grid, block, 0, stream>>>(X, Wk, Y);
}

// Round 6
// 113.383 us; speedup vs baseline: 1.1166x; 1.0239x over previous
//
#include <hip/hip_runtime.h>

// Fused: y1 = valid cross-corr(X,W) [4095x4095]; y2 = transposed-conv(y1,W) [4096x4096]
//   y2[i,j] = sum_{a,b} W[a,b]*y1(i-a,j-b), y1 masked to [0,4095)^2
//   y1(p,q) = W00*X[p][q] + W01*X[p][q+1] + W10*X[p+1][q] + W11*X[p+1][q+1]
//
// R5: kernel ~33.5us (4.1 TB/s) vs 22us floor. Traffic ideal; suspects are
// 10-concurrent-stream reads + mask VALU. This version: rolling 3-row window
// (1-2 streams/wave, ~56 VGPR -> 32 waves/CU) + wave-uniform interior fast
// path (87% of waves skip all masking/bounds logic). Identical fp math order.

#define HD 4096
#define RB 8       // output rows per thread

typedef float f32x4 __attribute__((ext_vector_type(4)));

template<bool INT>
__device__ __forceinline__ void load_row(const float* __restrict__ X, int row,
                                         int j0, int lane, f32x4& v, float& ev)
{
    ev = 0.f;
    if (INT || (unsigned)row < (unsigned)HD) {
        const float* rp = X + (size_t)row * HD;
        v = *reinterpret_cast<const f32x4*>(rp + j0);
        const int eoff = (lane == 0) ? (j0 - 1) : (j0 + 4);
        bool need = (lane == 0) || (lane == 63);
        if (!INT) need = need && (eoff >= 0) && (eoff < HD);
        if (need) ev = rp[eoff];          // single 2-lane masked load
    } else {
        v[0] = 0.f; v[1] = 0.f; v[2] = 0.f; v[3] = 0.f;  // OOB row -> zeros
    }
}

__device__ __forceinline__ void make_x(const f32x4 v, const float ev, int lane,
                                       float x[6])
{
    float lft = __shfl_up(v[3], 1);       // lane l-1's v.w
    float rgt = __shfl_down(v[0], 1);     // lane l+1's v.x
    if (lane == 0)  lft = ev;
    if (lane == 63) rgt = ev;
    x[0] = lft; x[1] = v[0]; x[2] = v[1]; x[3] = v[2]; x[4] = v[3]; x[5] = rgt;
}

template<bool INT>
__device__ __forceinline__ void y1_row(const float xa[6], const float xb[6],
                                       float w00, float w01, float w10, float w11,
                                       bool pv, bool lv, bool rv, float y[5])
{
    #pragma unroll
    for (int q = 0; q < 5; ++q) {
        float v = w00 * xa[q] + w01 * xa[q + 1]
                + w10 * xb[q] + w11 * xb[q + 1];
        if (!INT) {
            const bool ok = pv && (q != 0 || lv) && (q != 4 || rv);
            v = ok ? v : 0.f;
        }
        y[q] = v;
    }
}

template<bool INT>
__device__ __forceinline__ void tile(const float* __restrict__ X,
                                     float* __restrict__ Y,
                                     int i0, int j0, int lane,
                                     float w00, float w01, float w10, float w11)
{
    const bool lv = INT || (j0 > 0);
    const bool rv = INT || (j0 + 4 < HD);

    f32x4 v0, vnxt; float e0, enxt;
    load_row<INT>(X, i0 - 1, j0, lane, v0, e0);
    f32x4 vcur; float ecur;
    load_row<INT>(X, i0,     j0, lane, vcur, ecur);
    load_row<INT>(X, i0 + 1, j0, lane, vnxt, enxt);

    float xa[6], xb[6], xc[6];
    make_x(v0, e0, lane, xa);      // row i0-1
    make_x(vcur, ecur, lane, xb);  // row i0

    float y1p[5], y1c[5];
    y1_row<INT>(xa, xb, w00, w01, w10, w11, (i0 > 0), lv, rv, y1p);

    #pragma unroll
    for (int r = 0; r < RB; ++r) {
        const int i = i0 + r;
        f32x4 vpf; float epf;
        if (r < RB - 1)                                   // prefetch row i+2
            load_row<INT>(X, i + 2, j0, lane, vpf, epf);

        make_x(vnxt, enxt, lane, xc);                     // row i+1
        y1_row<INT>(xb, xc, w00, w01, w10, w11, (i < HD - 1), lv, rv, y1c);

        // y2[i,j0+t] = W00*y1(i,j)+W01*y1(i,j-1)+W10*y1(i-1,j)+W11*y1(i-1,j-1)
        f32x4 o;
        o[0] = w00 * y1c[1] + w01 * y1c[0] + w10 * y1p[1] + w11 * y1p[0];
        o[1] = w00 * y1c[2] + w01 * y1c[1] + w10 * y1p[2] + w11 * y1p[1];
        o[2] = w00 * y1c[3] + w01 * y1c[2] + w10 * y1p[3] + w11 * y1p[2];
        o[3] = w00 * y1c[4] + w01 * y1c[3] + w10 * y1p[4] + w11 * y1p[3];
        __builtin_nontemporal_store(o,
            reinterpret_cast<f32x4*>(Y + (size_t)i * HD + j0));

        #pragma unroll
        for (int q = 0; q < 5; ++q) y1p[q] = y1c[q];      // rename, not copy
        #pragma unroll
        for (int c = 0; c < 6; ++c) xb[c] = xc[c];
        if (r < RB - 1) { vnxt = vpf; enxt = epf; }
    }
}

__global__ __launch_bounds__(256) void fused_conv_kernel(
    const float* __restrict__ X, const float* __restrict__ Wk,
    float* __restrict__ Y)
{
    const int idx  = blockIdx.x * blockDim.x + threadIdx.x;
    const int i0   = (idx >> 10) * RB;          // output row-strip start
    const int j0   = (idx & 1023) << 2;         // first output col of quad
    const int lane = threadIdx.x & 63;

    const float w00 = Wk[0], w01 = Wk[1], w10 = Wk[2], w11 = Wk[3];

    // Wave-uniform interior test. Wave covers 64 consecutive quads; jw0 is
    // lane-0's j0. Interior waves need: all X rows i0-1..i0+RB in-bounds AND
    // all y1 rows i0-1..i0+RB-1 valid (i0 in [RB, HD-2*RB]) AND no lane
    // touching col 0 or col HD-4 (jw0 != 0, jw0 != HD-256).
    const int jw0 = ((idx & 1023) - lane) << 2;
    const bool interior = (i0 >= RB) && (i0 <= HD - 2 * RB) &&
                          (jw0 != 0) && (jw0 != HD - 256);

    if (interior) tile<true >(X, Y, i0, j0, lane, w00, w01, w10, w11);
    else          tile<false>(X, Y, i0, j0, lane, w00, w01, w10, w11);
}

extern "C" void kernel_launch(void* const* d_in, const int* in_sizes, int n_in,
                              void* d_out, int out_size, void* d_ws, size_t ws_size,
                              hipStream_t stream) {
    const float* X  = (const float*)d_in[0];
    const float* Wk = (const float*)d_in[1];
    float* Y        = (float*)d_out;

    const int total_threads = (HD / RB) * (HD / 4);   // 512 * 1024
    const int block = 256;
    const int grid  = total_threads / block;          // 2048 blocks
    fused_conv_kernel<<<grid, block, 0, stream>>>(X, Wk, Y);
}